// Round 5
// baseline (4704.323 us; speedup 1.0000x reference)
//
#include <hip/hip_runtime.h>
#include <math.h>

// Problem constants
#define B_   2048
#define T_   256
#define E_   124
#define V_   65
#define E2_  248
#define E3_  372
#define R_   8               // batch rows per block; packed-M rows 0-7=v1, 8-15=v2
#define NT_  512             // 8 waves
#define NB_  (B_ / R_)       // 256 blocks -> 1 per CU

#define NCT  24   // column tiles for 372 (16 each, padded 384)
#define NKC  4    // K chunks (K=124 padded to 128)
#define WM_NT 8
#define HD_NT 5
#define TCH  8    // timestep chunk for GX precompute

// ws offsets (in unsigned shorts); each frag block = 512 bf16 = 1KB
#define WS_WX  0                              // single split: 24 tiles x 4 chunks
#define WS_WM2 (WS_WX + NCT * NKC * 512)      // 49152  ; split-2: 2 x 24 x 4
#define WS_HH  (WS_WM2 + 2 * NCT * NKC * 512) // 147456 ; split-2
#define WS_WM  (WS_HH + 2 * NCT * NKC * 512)  // 245760 ; single: 8 x 4
#define WS_HD  (WS_WM + WM_NT * NKC * 512)    // 262144 ; single: 5 x 4
#define WS_END (WS_HD + HD_NT * NKC * 512)    // 272384 shorts = 544768 B

// LDS byte offsets (all 16B aligned)
#define HSTR 136   // row stride in shorts for m/h/y/xe
#define GSTR 9     // gate buffer col stride in floats
#define GXSTR 376  // GX row stride in shorts
#define L_M1 0
#define L_M2 2176
#define L_H1 4352
#define L_H2 6528
#define L_Y1 8704
#define L_Y2 10880
#define L_GIM 13056     // 384*9*4 = 13824
#define L_GHB 26880     // 13824
#define L_GX  40704     // [8][8][376] shorts = 48128
#define L_XE  88832     // [2][8][8][136] shorts = 34816
#define L_BSUM 123648   // 248 f
#define L_BIN  124640
#define L_BHN  125136
#define L_BM   125632
#define L_WP   126128
#define L_LNG  126624
#define L_LNB  127120
#define L_BHD  127616   // 65 f (pad to 288B)
#define L_P    127904
#define L_MU   127936
#define L_RS   127968
#define L_IDX  128000   // 8*256 int = 8192
#define SMEM_BYTES 136192

typedef __attribute__((ext_vector_type(8))) short short8v;
typedef __attribute__((ext_vector_type(4))) float float4v;

__device__ __forceinline__ unsigned short f2bf(float x) {
    unsigned u = __float_as_uint(x);
    unsigned r = (u + 0x7fffu + ((u >> 16) & 1u)) >> 16;
    return (unsigned short)r;
}
__device__ __forceinline__ float bf2f(unsigned short s) {
    return __uint_as_float(((unsigned)s) << 16);
}
__device__ __forceinline__ float sigmoid_f(float x) {
    return 1.0f / (1.0f + __expf(-x));
}
__device__ __forceinline__ float tanh_f(float x) {
    return 2.0f / (1.0f + __expf(-2.0f * x)) - 1.0f;
}

// Fragment layout: block of 512 bf16; lane l, reg j holds
// W[col = tile*16 + (l&15)][k = c*32 + (l>>4)*8 + j]  (zero-padded).
__global__ void prep_weights(const float* __restrict__ w_ih,
                             const float* __restrict__ w_hh,
                             const float* __restrict__ w_m,
                             const float* __restrict__ w_head,
                             unsigned short* __restrict__ ws) {
    for (int n = blockIdx.x * blockDim.x + threadIdx.x; n < WS_END;
         n += gridDim.x * blockDim.x) {
        const int r9 = n & 511;
        const int lane = r9 >> 3, j = r9 & 7;
        const int krel = (lane >> 4) * 8 + j;   // 0..31
        const int colrel = lane & 15;
        unsigned short v = 0;
        if (n < WS_WM2) {                 // WX: w_ih[:, 0:124], single bf16
            const int blk = n >> 9;
            const int tile = blk >> 2, c = blk & 3;
            const int k = c * 32 + krel, col = tile * 16 + colrel;
            const float w = (k < E_ && col < E3_) ? w_ih[col * E2_ + k] : 0.f;
            v = f2bf(w);
        } else if (n < WS_HH) {           // WM2: w_ih[:, 124:248], split-2
            const int blk = (n - WS_WM2) >> 9;
            const int spl = blk / 96, rest = blk - spl * 96;
            const int tile = rest >> 2, c = rest & 3;
            const int k = c * 32 + krel, col = tile * 16 + colrel;
            const float w = (k < E_ && col < E3_) ? w_ih[col * E2_ + E_ + k] : 0.f;
            const unsigned short w1 = f2bf(w);
            v = spl ? f2bf(w - bf2f(w1)) : w1;
        } else if (n < WS_WM) {           // HH: w_hh, split-2
            const int blk = (n - WS_HH) >> 9;
            const int spl = blk / 96, rest = blk - spl * 96;
            const int tile = rest >> 2, c = rest & 3;
            const int k = c * 32 + krel, col = tile * 16 + colrel;
            const float w = (k < E_ && col < E3_) ? w_hh[col * E_ + k] : 0.f;
            const unsigned short w1 = f2bf(w);
            v = spl ? f2bf(w - bf2f(w1)) : w1;
        } else if (n < WS_HD) {           // WM: w_m, single bf16
            const int blk = (n - WS_WM) >> 9;
            const int tile = blk >> 2, c = blk & 3;
            const int k = c * 32 + krel, col = tile * 16 + colrel;
            const float w = (k < E_ && col < E_) ? w_m[col * E_ + k] : 0.f;
            v = f2bf(w);
        } else {                          // HD: w_head, single bf16
            const int blk = (n - WS_HD) >> 9;
            const int tile = blk >> 2, c = blk & 3;
            const int k = c * 32 + krel, col = tile * 16 + colrel;
            const float w = (k < E_ && col < V_) ? w_head[col * E_ + k] : 0.f;
            v = f2bf(w);
        }
        ws[n] = v;
    }
}

__global__ void __launch_bounds__(NT_, 2)
gru_main(const int* __restrict__ idx, const float* __restrict__ tok,
         const float* __restrict__ pos,
         const float* __restrict__ b_ih, const float* __restrict__ b_hh,
         const float* __restrict__ w_p, const float* __restrict__ b_p,
         const float* __restrict__ b_m,
         const float* __restrict__ ln_g, const float* __restrict__ ln_b,
         const float* __restrict__ b_head,
         const unsigned short* __restrict__ ws, float* __restrict__ out) {
    extern __shared__ char smraw[];
    unsigned short* M1 = (unsigned short*)(smraw + L_M1);
    unsigned short* M2 = (unsigned short*)(smraw + L_M2);
    unsigned short* H1 = (unsigned short*)(smraw + L_H1);
    unsigned short* H2 = (unsigned short*)(smraw + L_H2);
    unsigned short* Y1 = (unsigned short*)(smraw + L_Y1);
    unsigned short* Y2 = (unsigned short*)(smraw + L_Y2);
    float* GIMs = (float*)(smraw + L_GIM);
    float* GHBs = (float*)(smraw + L_GHB);
    unsigned short* GXs = (unsigned short*)(smraw + L_GX);
    unsigned short* XEs = (unsigned short*)(smraw + L_XE);
    float* BSUMs = (float*)(smraw + L_BSUM);
    float* BINs = (float*)(smraw + L_BIN);
    float* BHNs = (float*)(smraw + L_BHN);
    float* BMs = (float*)(smraw + L_BM);
    float* WPs = (float*)(smraw + L_WP);
    float* LNGs = (float*)(smraw + L_LNG);
    float* LNBs = (float*)(smraw + L_LNB);
    float* BHDs = (float*)(smraw + L_BHD);
    float* Ps = (float*)(smraw + L_P);
    float* MUs = (float*)(smraw + L_MU);
    float* RSs = (float*)(smraw + L_RS);
    int* IDXs = (int*)(smraw + L_IDX);

    const int tid = threadIdx.x;
    const int lane = tid & 63;
    const int wv = tid >> 6;
    const int b0 = blockIdx.x * R_;
    const int frow = lane & 15;   // A row / B col / C col
    const int fgrp = lane >> 4;   // k-group / C row-group

    // ---- one-time staging ----
    for (int i = tid; i < E2_; i += NT_) BSUMs[i] = b_ih[i] + b_hh[i];
    for (int i = tid; i < E_; i += NT_) {
        BINs[i] = b_ih[E2_ + i];
        BHNs[i] = b_hh[E2_ + i];
        BMs[i] = b_m[i];
        WPs[i] = w_p[i];
        LNGs[i] = ln_g[i];
        LNBs[i] = ln_b[i];
    }
    for (int i = tid; i < V_; i += NT_) BHDs[i] = b_head[i];
    for (int i = tid; i < R_ * T_; i += NT_) IDXs[i] = idx[b0 * T_ + i];
    for (int i = tid; i < 6 * R_ * HSTR; i += NT_) M1[i] = 0;  // M1..Y2 contiguous
    for (int i = tid; i < 2 * TCH * R_ * HSTR; i += NT_) XEs[i] = 0;
    const float bp = b_p[0];

    // ---- permanent register caches ----
    short8v wm2f[2][3][4], hhf[2][3][4], hdf[4];
#pragma unroll
    for (int s = 0; s < 2; ++s)
#pragma unroll
        for (int ti = 0; ti < 3; ++ti)
#pragma unroll
            for (int c = 0; c < NKC; ++c) {
                wm2f[s][ti][c] = *(const short8v*)&ws[WS_WM2 + ((s * NCT + wv * 3 + ti) * NKC + c) * 512 + lane * 8];
                hhf[s][ti][c]  = *(const short8v*)&ws[WS_HH  + ((s * NCT + wv * 3 + ti) * NKC + c) * 512 + lane * 8];
            }
    {
        const int ht = (wv < HD_NT) ? wv : 0;
#pragma unroll
        for (int c = 0; c < NKC; ++c)
            hdf[c] = *(const short8v*)&ws[WS_HD + (ht * NKC + c) * 512 + lane * 8];
    }

    // per-lane packed-M source rows (rows 0-7 = high part, 8-15 = residual)
    const unsigned short* Mrow = (frow < 8 ? M1 : M2) + (frow & 7) * HSTR;
    const unsigned short* Hrow = (frow < 8 ? H1 : H2) + (frow & 7) * HSTR;
    const unsigned short* Yrow = (frow < 8 ? Y1 : Y2) + (frow & 7) * HSTR;
    const unsigned short* Xrow = XEs + (frow < 8 ? 0 : 1) * (TCH * R_ * HSTR) + (frow & 7) * HSTR;
    __syncthreads();

    for (int t = 0; t <= T_; ++t) {
        // ===== chunk phase (every 8 steps): GX[t..t+7] = W_x @ x =====
        if (t < T_ && (t & 7) == 0) {
            // build XE (bf16 split pairs of embeddings for 8 timesteps)
#pragma unroll
            for (int p = 0; p < 4; ++p) {
                const int i = tid + p * NT_;
                if (i < TCH * R_ * 31) {
                    const int q = i % 31;
                    const int rr = (i / 31) & 7;
                    const int mt = i / 248;
                    const int token = IDXs[rr * T_ + t + mt];
                    const int k = q * 4;
                    const float4 tv = *(const float4*)&tok[token * E_ + k];
                    const float4 pv = *(const float4*)&pos[(t + mt) * E_ + k];
#pragma unroll
                    for (int jj = 0; jj < 4; ++jj) {
                        const float x = ((const float*)&tv)[jj] + ((const float*)&pv)[jj];
                        const unsigned short x1 = f2bf(x);
                        XEs[((0 * TCH + mt) * R_ + rr) * HSTR + k + jj] = x1;
                        XEs[((1 * TCH + mt) * R_ + rr) * HSTR + k + jj] = f2bf(x - bf2f(x1));
                    }
                }
            }
            __syncthreads();
            // GEMM: each wave owns 3 column tiles; B streamed once per chunk
#pragma unroll
            for (int cti = 0; cti < 3; ++cti) {
                const int tile = wv * 3 + cti;
                short8v bx[4];
#pragma unroll
                for (int c = 0; c < NKC; ++c)
                    bx[c] = *(const short8v*)&ws[WS_WX + (tile * NKC + c) * 512 + lane * 8];
                for (int mt = 0; mt < TCH; ++mt) {
                    float4v ax = (float4v){0.f, 0.f, 0.f, 0.f};
#pragma unroll
                    for (int c = 0; c < NKC; ++c) {
                        const short8v a = *(const short8v*)&Xrow[mt * R_ * HSTR + c * 32 + fgrp * 8];
                        ax = __builtin_amdgcn_mfma_f32_16x16x32_bf16(a, bx[c], ax, 0, 0, 0);
                    }
                    const int col = tile * 16 + frow;
#pragma unroll
                    for (int j = 0; j < 4; ++j) {
                        const float v = ax[j] + __shfl_xor(ax[j], 32);
                        if (fgrp < 2 && col < E3_)
                            GXs[(mt * R_ + fgrp * 4 + j) * GXSTR + col] = f2bf(v);
                    }
                }
            }
            // no extra barrier: GX consumed only after the A->B barrier
        }

        // ===== phase A: gi_m + gh MFMAs (reg-cached B) + head for t-1 =====
        if (t < T_) {
            float4v acc[3];
            // gi_m = m @ w_ih[:,124:248]^T
#pragma unroll
            for (int ti = 0; ti < 3; ++ti) acc[ti] = (float4v){0.f, 0.f, 0.f, 0.f};
#pragma unroll
            for (int c = 0; c < NKC; ++c) {
                const short8v am = *(const short8v*)&Mrow[c * 32 + fgrp * 8];
#pragma unroll
                for (int ti = 0; ti < 3; ++ti) {
                    acc[ti] = __builtin_amdgcn_mfma_f32_16x16x32_bf16(am, wm2f[0][ti][c], acc[ti], 0, 0, 0);
                    acc[ti] = __builtin_amdgcn_mfma_f32_16x16x32_bf16(am, wm2f[1][ti][c], acc[ti], 0, 0, 0);
                }
            }
#pragma unroll
            for (int ti = 0; ti < 3; ++ti) {
                const int col = (wv * 3 + ti) * 16 + frow;
#pragma unroll
                for (int j = 0; j < 4; ++j) {
                    const float v = acc[ti][j] + __shfl_xor(acc[ti][j], 32);
                    if (fgrp < 2) GIMs[col * GSTR + fgrp * 4 + j] = v;
                }
            }
            // gh = h @ w_hh^T
#pragma unroll
            for (int ti = 0; ti < 3; ++ti) acc[ti] = (float4v){0.f, 0.f, 0.f, 0.f};
#pragma unroll
            for (int c = 0; c < NKC; ++c) {
                const short8v ah = *(const short8v*)&Hrow[c * 32 + fgrp * 8];
#pragma unroll
                for (int ti = 0; ti < 3; ++ti) {
                    acc[ti] = __builtin_amdgcn_mfma_f32_16x16x32_bf16(ah, hhf[0][ti][c], acc[ti], 0, 0, 0);
                    acc[ti] = __builtin_amdgcn_mfma_f32_16x16x32_bf16(ah, hhf[1][ti][c], acc[ti], 0, 0, 0);
                }
            }
#pragma unroll
            for (int ti = 0; ti < 3; ++ti) {
                const int col = (wv * 3 + ti) * 16 + frow;
#pragma unroll
                for (int j = 0; j < 4; ++j) {
                    const float v = acc[ti][j] + __shfl_xor(acc[ti][j], 32);
                    if (fgrp < 2) GHBs[col * GSTR + fgrp * 4 + j] = v;
                }
            }
        }
        // head for t-1 (y from D of t-1; B frags reg-cached, single bf16)
        if (t > 0 && wv < HD_NT) {
            float4v ahd = (float4v){0.f, 0.f, 0.f, 0.f};
#pragma unroll
            for (int c = 0; c < NKC; ++c) {
                const short8v ay = *(const short8v*)&Yrow[c * 32 + fgrp * 8];
                ahd = __builtin_amdgcn_mfma_f32_16x16x32_bf16(ay, hdf[c], ahd, 0, 0, 0);
            }
            const int v = wv * 16 + frow;
#pragma unroll
            for (int j = 0; j < 4; ++j) {
                const float val = ahd[j] + __shfl_xor(ahd[j], 32);
                if (fgrp < 2 && v < V_)
                    __builtin_nontemporal_store(
                        val + BHDs[v],
                        &out[((size_t)(b0 + fgrp * 4 + j) * T_ + (t - 1)) * V_ + v]);
            }
        }
        if (t == T_) break;
        __syncthreads();

        // ===== phase B: prefetch wm frags; gates -> h_new =====
        short8v wmf[4];
#pragma unroll
        for (int c = 0; c < NKC; ++c)
            wmf[c] = *(const short8v*)&ws[WS_WM + (wv * NKC + c) * 512 + lane * 8];
        {
            const int tl = t & 7;
#pragma unroll
            for (int k4 = 0; k4 < 2; ++k4) {
                const int i = tid + k4 * NT_;
                if (i < R_ * E_) {
                    const int r = i & 7, e = i >> 3;
                    const unsigned short* gxr_p = &GXs[(tl * R_ + r) * GXSTR];
                    const float gr = bf2f(gxr_p[e]) + GIMs[e * GSTR + r] + GHBs[e * GSTR + r] + BSUMs[e];
                    const float gz = bf2f(gxr_p[E_ + e]) + GIMs[(E_ + e) * GSTR + r] + GHBs[(E_ + e) * GSTR + r] + BSUMs[E_ + e];
                    const float gin = bf2f(gxr_p[E2_ + e]) + GIMs[(E2_ + e) * GSTR + r] + BINs[e];
                    const float ghn = GHBs[(E2_ + e) * GSTR + r] + BHNs[e];
                    const float rg = sigmoid_f(gr);
                    const float z = sigmoid_f(gz);
                    const float nn = tanh_f(gin + rg * ghn);
                    const float hold = bf2f(H1[r * HSTR + e]) + bf2f(H2[r * HSTR + e]);
                    const float hnew = (1.0f - z) * nn + z * hold;
                    const unsigned short h1v = f2bf(hnew);
                    H1[r * HSTR + e] = h1v;
                    H2[r * HSTR + e] = f2bf(hnew - bf2f(h1v));
                }
            }
        }
        __syncthreads();

        // ===== phase C: cand MFMA (single-bf16 wm) + p-dot + LN stats =====
        {
            float4v cc = (float4v){0.f, 0.f, 0.f, 0.f};
#pragma unroll
            for (int c = 0; c < NKC; ++c) {
                const short8v ah = *(const short8v*)&Hrow[c * 32 + fgrp * 8];
                cc = __builtin_amdgcn_mfma_f32_16x16x32_bf16(ah, wmf[c], cc, 0, 0, 0);
            }
            const int col = wv * 16 + frow;  // cand col, reuse GIMs
#pragma unroll
            for (int j = 0; j < 4; ++j) {
                const float v = cc[j] + __shfl_xor(cc[j], 32);
                if (fgrp < 2) GIMs[col * GSTR + fgrp * 4 + j] = v;
            }
            if (tid < 128) {
                const int r = tid >> 4, g = tid & 15;
                float s = 0.f;
                for (int e = g; e < E_; e += 16)
                    s += (bf2f(H1[r * HSTR + e]) + bf2f(H2[r * HSTR + e])) * WPs[e];
                s += __shfl_xor(s, 1);
                s += __shfl_xor(s, 2);
                s += __shfl_xor(s, 4);
                s += __shfl_xor(s, 8);
                if (g == 0) Ps[r] = sigmoid_f(s + bp);
            } else if (tid < 256) {
                const int r = (tid - 128) >> 4, g = tid & 15;
                float s1 = 0.f, s2 = 0.f;
                for (int e = g; e < E_; e += 16) {
                    const float h = bf2f(H1[r * HSTR + e]) + bf2f(H2[r * HSTR + e]);
                    s1 += h;
                    s2 += h * h;
                }
                s1 += __shfl_xor(s1, 1);
                s1 += __shfl_xor(s1, 2);
                s1 += __shfl_xor(s1, 4);
                s1 += __shfl_xor(s1, 8);
                s2 += __shfl_xor(s2, 1);
                s2 += __shfl_xor(s2, 2);
                s2 += __shfl_xor(s2, 4);
                s2 += __shfl_xor(s2, 8);
                if (g == 0) {
                    const float mu = s1 * (1.0f / (float)E_);
                    const float var = s2 * (1.0f / (float)E_) - mu * mu;
                    MUs[r] = mu;
                    RSs[r] = rsqrtf(var + 1e-5f);
                }
            }
        }
        __syncthreads();

        // ===== phase D: m update + y = LN(h_new) =====
#pragma unroll
        for (int k4 = 0; k4 < 2; ++k4) {
            const int i = tid + k4 * NT_;
            if (i < R_ * E_) {
                const int r = i & 7, e = i >> 3;
                const float cand = tanh_f(GIMs[e * GSTR + r] + BMs[e]);
                const float pv = Ps[r];
                const float mold = bf2f(M1[r * HSTR + e]) + bf2f(M2[r * HSTR + e]);
                const float mnew = (1.0f - pv) * mold + pv * cand;
                const unsigned short m1v = f2bf(mnew);
                M1[r * HSTR + e] = m1v;
                M2[r * HSTR + e] = f2bf(mnew - bf2f(m1v));
                const float hv = bf2f(H1[r * HSTR + e]) + bf2f(H2[r * HSTR + e]);
                const float yv = (hv - MUs[r]) * RSs[r] * LNGs[e] + LNBs[e];
                const unsigned short y1v = f2bf(yv);
                Y1[r * HSTR + e] = y1v;
                Y2[r * HSTR + e] = f2bf(yv - bf2f(y1v));
            }
        }
        __syncthreads();
    }
}

extern "C" void kernel_launch(void* const* d_in, const int* in_sizes, int n_in,
                              void* d_out, int out_size, void* d_ws, size_t ws_size,
                              hipStream_t stream) {
    const int* idx = (const int*)d_in[0];
    const float* tok = (const float*)d_in[1];
    const float* pos = (const float*)d_in[2];
    const float* w_ih = (const float*)d_in[3];
    const float* w_hh = (const float*)d_in[4];
    const float* b_ih = (const float*)d_in[5];
    const float* b_hh = (const float*)d_in[6];
    const float* w_p = (const float*)d_in[7];
    const float* b_p = (const float*)d_in[8];
    const float* w_m = (const float*)d_in[9];
    const float* b_m = (const float*)d_in[10];
    const float* ln_g = (const float*)d_in[11];
    const float* ln_b = (const float*)d_in[12];
    const float* w_head = (const float*)d_in[13];
    const float* b_head = (const float*)d_in[14];
    float* out = (float*)d_out;
    unsigned short* ws = (unsigned short*)d_ws;

    prep_weights<<<532, 256, 0, stream>>>(w_ih, w_hh, w_m, w_head, ws);

    (void)hipFuncSetAttribute((const void*)gru_main,
                              hipFuncAttributeMaxDynamicSharedMemorySize,
                              SMEM_BYTES);
    gru_main<<<NB_, NT_, SMEM_BYTES, stream>>>(idx, tok, pos, b_ih, b_hh, w_p, b_p,
                                               b_m, ln_g, ln_b, b_head, ws, out);
}

// Round 8
// 1358.212 us; speedup vs baseline: 3.4636x; 3.4636x over previous
//
#include <hip/hip_runtime.h>
#include <math.h>

// Problem constants
#define B_   2048
#define T_   256
#define E_   124
#define V_   65
#define E2_  248
#define E3_  372
#define R_   8               // batch rows per block; packed-M rows 0-7=hi, 8-15=residual
#define NT_  512             // 8 waves
#define NB_  (B_ / R_)       // 256 blocks -> 1 per CU
#define NKC  4               // K chunks (124 padded to 128)
#define TCH  8               // timestep chunk for GX precompute

// ws offsets (unsigned shorts); frag block = 512 bf16 = 1KB
// gate-major tiling for WX/WM2/HH: block id = ((g*8 + tt)*4 + c)
//   holds W[col = g*124 + tt*16 + (lane&15)][k = c*32 + (lane>>4)*8 + j]
#define WS_WX  0                    // 24*4*512 = 49152
#define WS_WM2 49152
#define WS_HH  98304
#define WS_WM  147456               // 8*4*512 = 16384 (tile tt: col=tt*16+..)
#define WS_HD  163840               // 5*4*512 = 10240
#define WS_END 174080               // shorts = 348160 B

// LDS byte offsets
#define HSTR 136    // row stride (shorts) for m/h/y/xe state rows
#define GXSTR 376   // GX row stride (shorts)
#define L_M1  0
#define L_M2  2176
#define L_HA1 4352
#define L_HA2 6528
#define L_HB1 8704
#define L_HB2 10880
#define L_Y1  13056
#define L_Y2  15232     // state block ends 17408
#define L_GX  17408     // [8][8][376] shorts = 48128 B -> ends 65536
#define L_XE  65536     // [2][8][8][136] shorts = 34816 B -> ends 100352
#define L_BRZ 100352    // 248 f
#define L_BIN 101344    // 124 f
#define L_BHN 101840
#define L_BM  102336
#define L_WP  102832
#define L_LNG 103328
#define L_LNB 103824
#define L_BHD 104320    // 68 f
#define L_P   104592    // 8 f
#define L_MU  104624
#define L_RS  104656
#define L_IDX 104704    // 8*256 int = 8192
#define SMEM_BYTES 112896

typedef __attribute__((ext_vector_type(8))) short short8v;
typedef __attribute__((ext_vector_type(4))) float float4v;

__device__ __forceinline__ unsigned short f2bf(float x) {
    unsigned u = __float_as_uint(x);
    unsigned r = (u + 0x7fffu + ((u >> 16) & 1u)) >> 16;
    return (unsigned short)r;
}
__device__ __forceinline__ float bf2f(unsigned short s) {
    return __uint_as_float(((unsigned)s) << 16);
}
__device__ __forceinline__ float sigmoid_f(float x) {
    return 1.0f / (1.0f + __expf(-x));
}
__device__ __forceinline__ float tanh_f(float x) {
    return 2.0f / (1.0f + __expf(-2.0f * x)) - 1.0f;
}

__global__ void prep_weights(const float* __restrict__ w_ih,
                             const float* __restrict__ w_hh,
                             const float* __restrict__ w_m,
                             const float* __restrict__ w_head,
                             unsigned short* __restrict__ ws) {
    for (int n = blockIdx.x * blockDim.x + threadIdx.x; n < WS_END;
         n += gridDim.x * blockDim.x) {
        const int r9 = n & 511;
        const int lane = r9 >> 3, j = r9 & 7;
        const int krel = (lane >> 4) * 8 + j;   // 0..31
        const int colrel = lane & 15;
        float w = 0.f;
        if (n < WS_WM2) {                       // WX: w_ih[:, 0:124]
            const int blk = n >> 9;
            const int c = blk & 3, tt = (blk >> 2) & 7, g = blk >> 5;
            const int k = c * 32 + krel, e = tt * 16 + colrel;
            if (k < E_ && e < E_) w = w_ih[(g * E_ + e) * E2_ + k];
        } else if (n < WS_HH) {                 // WM2: w_ih[:, 124:248]
            const int blk = (n - WS_WM2) >> 9;
            const int c = blk & 3, tt = (blk >> 2) & 7, g = blk >> 5;
            const int k = c * 32 + krel, e = tt * 16 + colrel;
            if (k < E_ && e < E_) w = w_ih[(g * E_ + e) * E2_ + E_ + k];
        } else if (n < WS_WM) {                 // HH: w_hh
            const int blk = (n - WS_HH) >> 9;
            const int c = blk & 3, tt = (blk >> 2) & 7, g = blk >> 5;
            const int k = c * 32 + krel, e = tt * 16 + colrel;
            if (k < E_ && e < E_) w = w_hh[(g * E_ + e) * E_ + k];
        } else if (n < WS_HD) {                 // WM: w_m (cand)
            const int blk = (n - WS_WM) >> 9;
            const int c = blk & 3, tt = blk >> 2;
            const int k = c * 32 + krel, e = tt * 16 + colrel;
            if (k < E_ && e < E_) w = w_m[e * E_ + k];
        } else {                                // HD: w_head
            const int blk = (n - WS_HD) >> 9;
            const int c = blk & 3, tt = blk >> 2;
            const int k = c * 32 + krel, v = tt * 16 + colrel;
            if (k < E_ && v < V_) w = w_head[v * E_ + k];
        }
        ws[n] = f2bf(w);
    }
}

__global__ void __launch_bounds__(NT_, 2)
gru_main(const int* __restrict__ idx, const float* __restrict__ tok,
         const float* __restrict__ pos,
         const float* __restrict__ b_ih, const float* __restrict__ b_hh,
         const float* __restrict__ w_p, const float* __restrict__ b_p,
         const float* __restrict__ b_m,
         const float* __restrict__ ln_g, const float* __restrict__ ln_b,
         const float* __restrict__ b_head,
         const unsigned short* __restrict__ ws, float* __restrict__ out) {
    extern __shared__ char smraw[];
    unsigned short* M1 = (unsigned short*)(smraw + L_M1);
    unsigned short* M2 = (unsigned short*)(smraw + L_M2);
    unsigned short* Y1 = (unsigned short*)(smraw + L_Y1);
    unsigned short* Y2 = (unsigned short*)(smraw + L_Y2);
    unsigned short* GXs = (unsigned short*)(smraw + L_GX);
    unsigned short* XEs = (unsigned short*)(smraw + L_XE);
    float* BRZs = (float*)(smraw + L_BRZ);
    float* BINs = (float*)(smraw + L_BIN);
    float* BHNs = (float*)(smraw + L_BHN);
    float* BMs = (float*)(smraw + L_BM);
    float* WPs = (float*)(smraw + L_WP);
    float* LNGs = (float*)(smraw + L_LNG);
    float* LNBs = (float*)(smraw + L_LNB);
    float* BHDs = (float*)(smraw + L_BHD);
    float* Ps = (float*)(smraw + L_P);
    float* MUs = (float*)(smraw + L_MU);
    float* RSs = (float*)(smraw + L_RS);
    int* IDXs = (int*)(smraw + L_IDX);

    const int tid = threadIdx.x;
    const int lane = tid & 63;
    const int wv = tid >> 6;
    const int b0 = blockIdx.x * R_;
    const int frow = lane & 15;       // A row / C col
    const int fgrp = lane >> 4;       // k-group / C row-group
    const int eo = wv * 16 + frow;    // owned e (gate/cand column)
    const bool act = (fgrp < 2) && (eo < E_);

    // ---- one-time staging ----
    for (int i = tid; i < E2_; i += NT_) BRZs[i] = b_ih[i] + b_hh[i];
    for (int i = tid; i < E_; i += NT_) {
        BINs[i] = b_ih[E2_ + i];
        BHNs[i] = b_hh[E2_ + i];
        BMs[i] = b_m[i];
        WPs[i] = w_p[i];
        LNGs[i] = ln_g[i];
        LNBs[i] = ln_b[i];
    }
    for (int i = tid; i < V_; i += NT_) BHDs[i] = b_head[i];
    for (int i = tid; i < R_ * T_; i += NT_) IDXs[i] = idx[b0 * T_ + i];
    // zero state block (M1..Y2 contiguous: 8 buffers * 1088 shorts)
    for (int i = tid; i < 8704; i += NT_) ((unsigned short*)smraw)[i] = 0;
    for (int i = tid; i < 2 * TCH * R_ * HSTR; i += NT_) XEs[i] = 0;
    const float bp = b_p[0];

    // ---- permanent register caches: 96 VGPR total (R4-proven level) ----
    short8v hhf[3][NKC], wm2f[3][NKC];
#pragma unroll
    for (int g = 0; g < 3; ++g)
#pragma unroll
        for (int c = 0; c < NKC; ++c) {
            hhf[g][c]  = *(const short8v*)&ws[WS_HH  + ((g * 8 + wv) * NKC + c) * 512 + lane * 8];
            wm2f[g][c] = *(const short8v*)&ws[WS_WM2 + ((g * 8 + wv) * NKC + c) * 512 + lane * 8];
        }

    // per-lane packed-M source rows (frow 0-7 = hi part, 8-15 = residual)
    const unsigned short* Mrow = (frow < 8 ? M1 : M2) + (frow & 7) * HSTR;
    const unsigned short* Yrow = (frow < 8 ? Y1 : Y2) + (frow & 7) * HSTR;
    const unsigned short* Xrow = XEs + (frow < 8 ? 0 : 1) * (TCH * R_ * HSTR) + (frow & 7) * HSTR;
    __syncthreads();

    float hnewv[4] = {0.f, 0.f, 0.f, 0.f};
    float candv[4] = {0.f, 0.f, 0.f, 0.f};

    for (int t = 0; t <= T_; ++t) {
        const int hw = t & 1;
        unsigned short* Hw1 = (unsigned short*)(smraw + (hw ? L_HB1 : L_HA1));
        unsigned short* Hw2 = (unsigned short*)(smraw + (hw ? L_HB2 : L_HA2));
        const unsigned short* Hr1 = (const unsigned short*)(smraw + (hw ? L_HA1 : L_HB1));
        const unsigned short* Hr2 = (const unsigned short*)(smraw + (hw ? L_HA2 : L_HB2));
        const unsigned short* Hrow = (frow < 8 ? Hr1 : Hr2) + (frow & 7) * HSTR;
        const unsigned short* Hwrow = (frow < 8 ? (const unsigned short*)Hw1
                                                : (const unsigned short*)Hw2) + (frow & 7) * HSTR;

        // ===== chunk phase (every 8 steps): GX[t..t+7] = W_x @ x =====
        if (t < T_ && (t & 7) == 0) {
#pragma unroll
            for (int p = 0; p < 4; ++p) {
                const int i = tid + p * NT_;
                if (i < TCH * R_ * 31) {
                    const int mt = i / 248;
                    const int rem = i - mt * 248;
                    const int rr = rem / 31, q = rem - (rem / 31) * 31;
                    const int token = IDXs[rr * T_ + t + mt];
                    const int k = q * 4;
                    const float4 tv = *(const float4*)&tok[token * E_ + k];
                    const float4 pv = *(const float4*)&pos[(t + mt) * E_ + k];
#pragma unroll
                    for (int jj = 0; jj < 4; ++jj) {
                        const float x = ((const float*)&tv)[jj] + ((const float*)&pv)[jj];
                        const unsigned short x1 = f2bf(x);
                        XEs[((0 * TCH + mt) * R_ + rr) * HSTR + k + jj] = x1;
                        XEs[((1 * TCH + mt) * R_ + rr) * HSTR + k + jj] = f2bf(x - bf2f(x1));
                    }
                }
            }
            __syncthreads();
#pragma unroll
            for (int g = 0; g < 3; ++g) {
                short8v bx[NKC];
#pragma unroll
                for (int c = 0; c < NKC; ++c)
                    bx[c] = *(const short8v*)&ws[WS_WX + ((g * 8 + wv) * NKC + c) * 512 + lane * 8];
                for (int mt = 0; mt < TCH; ++mt) {
                    float4v ax = (float4v){0.f, 0.f, 0.f, 0.f};
#pragma unroll
                    for (int c = 0; c < NKC; ++c) {
                        const short8v a = *(const short8v*)&Xrow[mt * R_ * HSTR + c * 32 + fgrp * 8];
                        ax = __builtin_amdgcn_mfma_f32_16x16x32_bf16(a, bx[c], ax, 0, 0, 0);
                    }
#pragma unroll
                    for (int j = 0; j < 4; ++j) {
                        const float v = ax[j] + __shfl_xor(ax[j], 32);
                        if (act) GXs[(mt * R_ + fgrp * 4 + j) * GXSTR + g * E_ + eo] = f2bf(v);
                    }
                }
            }
            // GX consumed wave-locally (same wave wrote its own gate columns)
        }

        // ===== phase A: gi_m/gh MFMAs + in-register gates =====
        if (t < T_) {
            short8v am[NKC], ah[NKC];
#pragma unroll
            for (int c = 0; c < NKC; ++c) {
                am[c] = *(const short8v*)&Mrow[c * 32 + fgrp * 8];
                ah[c] = *(const short8v*)&Hrow[c * 32 + fgrp * 8];
            }
            float4v accm[3], acch[3];
#pragma unroll
            for (int g = 0; g < 3; ++g) {
                accm[g] = (float4v){0.f, 0.f, 0.f, 0.f};
                acch[g] = (float4v){0.f, 0.f, 0.f, 0.f};
            }
#pragma unroll
            for (int g = 0; g < 3; ++g)
#pragma unroll
                for (int c = 0; c < NKC; ++c) {
                    accm[g] = __builtin_amdgcn_mfma_f32_16x16x32_bf16(am[c], wm2f[g][c], accm[g], 0, 0, 0);
                    acch[g] = __builtin_amdgcn_mfma_f32_16x16x32_bf16(ah[c], hhf[g][c], acch[g], 0, 0, 0);
                }

            // combine packed-M split rows
            float gm[3][4], gh2[3][4];
#pragma unroll
            for (int g = 0; g < 3; ++g)
#pragma unroll
                for (int j = 0; j < 4; ++j) {
                    gm[g][j] = accm[g][j] + __shfl_xor(accm[g][j], 32);
                    gh2[g][j] = acch[g][j] + __shfl_xor(acch[g][j], 32);
                }
            // gates fully in-register (lane owns e=eo, rows fgrp*4+j)
            if (act) {
                const float brz0 = BRZs[eo], brz1 = BRZs[E_ + eo];
                const float bin = BINs[eo], bhn = BHNs[eo];
                const int gxbase = ((t & 7) * R_ + fgrp * 4) * GXSTR;
#pragma unroll
                for (int j = 0; j < 4; ++j) {
                    const int r = fgrp * 4 + j;
                    const unsigned short* gxp = &GXs[gxbase + j * GXSTR];
                    const float rg = sigmoid_f(bf2f(gxp[eo]) + gm[0][j] + gh2[0][j] + brz0);
                    const float z = sigmoid_f(bf2f(gxp[E_ + eo]) + gm[1][j] + gh2[1][j] + brz1);
                    const float nn = tanh_f(bf2f(gxp[E2_ + eo]) + gm[2][j] + bin + rg * (gh2[2][j] + bhn));
                    const float hold = bf2f(Hr1[r * HSTR + eo]) + bf2f(Hr2[r * HSTR + eo]);
                    const float hv = (1.0f - z) * nn + z * hold;
                    hnewv[j] = hv;
                    const unsigned short h1 = f2bf(hv);
                    Hw1[r * HSTR + eo] = h1;
                    Hw2[r * HSTR + eo] = f2bf(hv - bf2f(h1));
                }
            }
        }

        // ===== head logits for step t-1 — MUST run at t == T_ too =====
        if (t > 0 && wv < 5) {
            float4v ahd = (float4v){0.f, 0.f, 0.f, 0.f};
#pragma unroll
            for (int c = 0; c < NKC; ++c) {
                const short8v ay = *(const short8v*)&Yrow[c * 32 + fgrp * 8];
                const short8v bh = *(const short8v*)&ws[WS_HD + (wv * NKC + c) * 512 + lane * 8];
                ahd = __builtin_amdgcn_mfma_f32_16x16x32_bf16(ay, bh, ahd, 0, 0, 0);
            }
#pragma unroll
            for (int j = 0; j < 4; ++j) {
                const float val = ahd[j] + __shfl_xor(ahd[j], 32);
                if (fgrp < 2 && eo < V_)
                    __builtin_nontemporal_store(
                        val + BHDs[eo],
                        &out[((size_t)(b0 + fgrp * 4 + j) * T_ + (t - 1)) * V_ + eo]);
            }
        }
        if (t == T_) break;
        __syncthreads();

        // ===== phase C: cand MFMA (w_m streamed) + p-dot + LN stats =====
        {
            float4v cc = (float4v){0.f, 0.f, 0.f, 0.f};
#pragma unroll
            for (int c = 0; c < NKC; ++c) {
                const short8v ahw = *(const short8v*)&Hwrow[c * 32 + fgrp * 8];
                const short8v bm = *(const short8v*)&ws[WS_WM + (wv * NKC + c) * 512 + lane * 8];
                cc = __builtin_amdgcn_mfma_f32_16x16x32_bf16(ahw, bm, cc, 0, 0, 0);
            }
#pragma unroll
            for (int j = 0; j < 4; ++j) candv[j] = cc[j] + __shfl_xor(cc[j], 32);

            if (tid < 128) {
                const int r = tid >> 4, g = tid & 15;
                float s = 0.f;
                for (int e = g; e < E_; e += 16)
                    s += (bf2f(Hw1[r * HSTR + e]) + bf2f(Hw2[r * HSTR + e])) * WPs[e];
                s += __shfl_xor(s, 1);
                s += __shfl_xor(s, 2);
                s += __shfl_xor(s, 4);
                s += __shfl_xor(s, 8);
                if (g == 0) Ps[r] = sigmoid_f(s + bp);
            } else if (tid < 256) {
                const int r = (tid - 128) >> 4, g = tid & 15;
                float s1 = 0.f, s2 = 0.f;
                for (int e = g; e < E_; e += 16) {
                    const float h = bf2f(Hw1[r * HSTR + e]) + bf2f(Hw2[r * HSTR + e]);
                    s1 += h;
                    s2 += h * h;
                }
                s1 += __shfl_xor(s1, 1);
                s1 += __shfl_xor(s1, 2);
                s1 += __shfl_xor(s1, 4);
                s1 += __shfl_xor(s1, 8);
                s2 += __shfl_xor(s2, 1);
                s2 += __shfl_xor(s2, 2);
                s2 += __shfl_xor(s2, 4);
                s2 += __shfl_xor(s2, 8);
                if (g == 0) {
                    const float mu = s1 * (1.0f / (float)E_);
                    const float var = s2 * (1.0f / (float)E_) - mu * mu;
                    MUs[r] = mu;
                    RSs[r] = rsqrtf(var + 1e-5f);
                }
            }
        }
        __syncthreads();

        // ===== phase D: m update + y = LN(h_new) (fragment-register layout) =====
        if (act) {
            const float bm = BMs[eo], lng = LNGs[eo], lnb = LNBs[eo];
#pragma unroll
            for (int j = 0; j < 4; ++j) {
                const int r = fgrp * 4 + j;
                const float pv = Ps[r];
                const float cand = tanh_f(candv[j] + bm);
                const float mold = bf2f(M1[r * HSTR + eo]) + bf2f(M2[r * HSTR + eo]);
                const float mnew = (1.0f - pv) * mold + pv * cand;
                const unsigned short m1v = f2bf(mnew);
                M1[r * HSTR + eo] = m1v;
                M2[r * HSTR + eo] = f2bf(mnew - bf2f(m1v));
                const float yv = (hnewv[j] - MUs[r]) * RSs[r] * lng + lnb;
                const unsigned short y1v = f2bf(yv);
                Y1[r * HSTR + eo] = y1v;
                Y2[r * HSTR + eo] = f2bf(yv - bf2f(y1v));
            }
        }
        __syncthreads();
    }
}

extern "C" void kernel_launch(void* const* d_in, const int* in_sizes, int n_in,
                              void* d_out, int out_size, void* d_ws, size_t ws_size,
                              hipStream_t stream) {
    const int* idx = (const int*)d_in[0];
    const float* tok = (const float*)d_in[1];
    const float* pos = (const float*)d_in[2];
    const float* w_ih = (const float*)d_in[3];
    const float* w_hh = (const float*)d_in[4];
    const float* b_ih = (const float*)d_in[5];
    const float* b_hh = (const float*)d_in[6];
    const float* w_p = (const float*)d_in[7];
    const float* b_p = (const float*)d_in[8];
    const float* w_m = (const float*)d_in[9];
    const float* b_m = (const float*)d_in[10];
    const float* ln_g = (const float*)d_in[11];
    const float* ln_b = (const float*)d_in[12];
    const float* w_head = (const float*)d_in[13];
    const float* b_head = (const float*)d_in[14];
    float* out = (float*)d_out;
    unsigned short* ws = (unsigned short*)d_ws;

    prep_weights<<<680, 256, 0, stream>>>(w_ih, w_hh, w_m, w_head, ws);

    (void)hipFuncSetAttribute((const void*)gru_main,
                              hipFuncAttributeMaxDynamicSharedMemorySize,
                              SMEM_BYTES);
    gru_main<<<NB_, NT_, SMEM_BYTES, stream>>>(idx, tok, pos, b_ih, b_hh, w_p, b_p,
                                               b_m, ln_g, ln_b, b_head, ws, out);
}